// Round 7
// baseline (443.385 us; speedup 1.0000x reference)
//
#include <hip/hip_runtime.h>
#include <hip/hip_bf16.h>
#include <cstdint>
#include <cstddef>

#define S_LEN 2048
#define D_HEAD 64
#define NBH 32                      // B*H = 2*16
#define NELEM 4194304               // NBH * S_LEN * D_HEAD
#define PCOLS 512                   // columns per panel phase

typedef __attribute__((ext_vector_type(8))) short short8;
typedef __attribute__((ext_vector_type(4))) float f32x4;

__device__ __forceinline__ short f2bf(float f) {
    union { float f; uint32_t u; } v; v.f = f;
    uint32_t u = v.u + 0x7FFFu + ((v.u >> 16) & 1u);   // RNE, inputs finite
    return (short)(u >> 16);
}

__device__ __forceinline__ uint32_t pkbf(float lo, float hi) {
    return ((uint32_t)(uint16_t)f2bf(hi) << 16) | (uint32_t)(uint16_t)f2bf(lo);
}

// K fp32 -> bf16, same layout
__global__ void convert_k_kernel(const float* __restrict__ K, short* __restrict__ Kb) {
    int i = blockIdx.x * 256 + threadIdx.x;
    float4 x = reinterpret_cast<const float4*>(K)[i];
    short4 y;
    y.x = f2bf(x.x); y.y = f2bf(x.y); y.z = f2bf(x.z); y.w = f2bf(x.w);
    reinterpret_cast<short4*>(Kb)[i] = y;
}

// V fp32 [bh][S][D] -> bf16 transposed [bh][D][S]
__global__ void transpose_v_kernel(const float* __restrict__ V, short* __restrict__ Vtb) {
    __shared__ float tile[64][65];
    const int bh = blockIdx.y;
    const int s0 = blockIdx.x * 64;
    const int d = threadIdx.x & 63;
    const int r = threadIdx.x >> 6;
    const float* vp = V + ((size_t)bh * S_LEN + s0) * D_HEAD;
    #pragma unroll
    for (int i = 0; i < 16; ++i) {
        int s = i * 4 + r;
        tile[s][d] = vp[(size_t)s * D_HEAD + d];
    }
    __syncthreads();
    short* op = Vtb + (size_t)bh * (D_HEAD * S_LEN) + s0;
    #pragma unroll
    for (int i = 0; i < 16; ++i) {
        int dd = i * 4 + r;
        op[(size_t)dd * S_LEN + d] = f2bf(tile[d][dd]);
    }
}

// Kernel A: softmax denominator + PV + Out; writes rl = 1/l per q-row to Rl.
// (unchanged, validated in R4-R6)
__launch_bounds__(256, 4)
__global__ void attn_pv_kernel(const float* __restrict__ Q,
                               const short* __restrict__ Kb,
                               const short* __restrict__ Vtb,
                               float* __restrict__ Out,
                               float* __restrict__ Rl) {
    const int lane = threadIdx.x & 63;
    const int w    = threadIdx.x >> 6;
    const int bh   = blockIdx.y;
    const int qbase = blockIdx.x * 64 + w * 16;
    const int lrow = lane & 15;
    const int lgrp = lane >> 4;
    const float scale = 0.125f;                        // 1/sqrt(64)

    short8 q0, q1;
    {
        const float* qr = Q + ((size_t)bh * S_LEN + qbase + lrow) * D_HEAD + lgrp * 8;
        #pragma unroll
        for (int e = 0; e < 8; ++e) q0[e] = f2bf(qr[e]);
        #pragma unroll
        for (int e = 0; e < 8; ++e) q1[e] = f2bf(qr[e + 32]);
    }

    const short* Kp = Kb + (size_t)bh * (S_LEN * D_HEAD);
    const short* Vp = Vtb + (size_t)bh * (D_HEAD * S_LEN);

    const int srcA = ((lane & 15) + ((lane >> 4) & 1) * 32) << 2;
    const int srcB = srcA + (16 << 2);
    const bool glow = (lgrp < 2);

    float l = 0.f;
    f32x4 acc[4] = {};
    for (int j0 = 0; j0 < S_LEN; j0 += 32) {
        const short* kr0 = Kp + (size_t)(j0 + lrow) * D_HEAD + lgrp * 8;
        const short* kr1 = kr0 + 16 * D_HEAD;
        short8 k00 = *reinterpret_cast<const short8*>(kr0);
        short8 k01 = *reinterpret_cast<const short8*>(kr0 + 32);
        short8 k10 = *reinterpret_cast<const short8*>(kr1);
        short8 k11 = *reinterpret_cast<const short8*>(kr1 + 32);
        short8 bv0 = *reinterpret_cast<const short8*>(Vp + (size_t)(0 * 16 + lrow) * S_LEN + j0 + lgrp * 8);
        short8 bv1 = *reinterpret_cast<const short8*>(Vp + (size_t)(1 * 16 + lrow) * S_LEN + j0 + lgrp * 8);
        short8 bv2 = *reinterpret_cast<const short8*>(Vp + (size_t)(2 * 16 + lrow) * S_LEN + j0 + lgrp * 8);
        short8 bv3 = *reinterpret_cast<const short8*>(Vp + (size_t)(3 * 16 + lrow) * S_LEN + j0 + lgrp * 8);
        f32x4 c0 = {0.f, 0.f, 0.f, 0.f};
        f32x4 c1 = {0.f, 0.f, 0.f, 0.f};
        c0 = __builtin_amdgcn_mfma_f32_16x16x32_bf16(k00, q0, c0, 0, 0, 0);
        c0 = __builtin_amdgcn_mfma_f32_16x16x32_bf16(k01, q1, c0, 0, 0, 0);
        c1 = __builtin_amdgcn_mfma_f32_16x16x32_bf16(k10, q0, c1, 0, 0, 0);
        c1 = __builtin_amdgcn_mfma_f32_16x16x32_bf16(k11, q1, c1, 0, 0, 0);

        float e0[4], e1[4];
        #pragma unroll
        for (int rr = 0; rr < 4; ++rr) {
            e0[rr] = __expf(c0[rr] * scale);
            e1[rr] = __expf(c1[rr] * scale);
            l += e0[rr] + e1[rr];
        }
        int w00 = (int)pkbf(e0[0], e0[1]);
        int w01 = (int)pkbf(e0[2], e0[3]);
        int w10 = (int)pkbf(e1[0], e1[1]);
        int w11 = (int)pkbf(e1[2], e1[3]);
        int t0 = __builtin_amdgcn_ds_bpermute(srcA, w00);
        int t1 = __builtin_amdgcn_ds_bpermute(srcA, w01);
        int t2 = __builtin_amdgcn_ds_bpermute(srcB, w00);
        int t3 = __builtin_amdgcn_ds_bpermute(srcB, w01);
        int u0 = __builtin_amdgcn_ds_bpermute(srcA, w10);
        int u1 = __builtin_amdgcn_ds_bpermute(srcA, w11);
        int u2 = __builtin_amdgcn_ds_bpermute(srcB, w10);
        int u3 = __builtin_amdgcn_ds_bpermute(srcB, w11);
        union { short8 s8; int wd[4]; } fr;
        fr.wd[0] = glow ? t0 : u0;
        fr.wd[1] = glow ? t1 : u1;
        fr.wd[2] = glow ? t2 : u2;
        fr.wd[3] = glow ? t3 : u3;

        acc[0] = __builtin_amdgcn_mfma_f32_16x16x32_bf16(fr.s8, bv0, acc[0], 0, 0, 0);
        acc[1] = __builtin_amdgcn_mfma_f32_16x16x32_bf16(fr.s8, bv1, acc[1], 0, 0, 0);
        acc[2] = __builtin_amdgcn_mfma_f32_16x16x32_bf16(fr.s8, bv2, acc[2], 0, 0, 0);
        acc[3] = __builtin_amdgcn_mfma_f32_16x16x32_bf16(fr.s8, bv3, acc[3], 0, 0, 0);
    }
    l += __shfl_xor(l, 16);
    l += __shfl_xor(l, 32);
    const float rl = 1.0f / l;                         // denominator for q = lrow

    if (lgrp == 0) Rl[(size_t)bh * S_LEN + qbase + lrow] = rl;

    float rlo[4];
    #pragma unroll
    for (int rr = 0; rr < 4; ++rr) rlo[rr] = __shfl(rl, lgrp * 4 + rr);

    float* ob = Out + ((size_t)bh * S_LEN + qbase + lgrp * 4) * D_HEAD + lrow;
    #pragma unroll
    for (int vt = 0; vt < 4; ++vt) {
        #pragma unroll
        for (int rr = 0; rr < 4; ++rr) {
            ob[(size_t)rr * D_HEAD + vt * 16] = acc[vt][rr] * rlo[rr];
        }
    }
}

// Kernel B: producer/consumer P-writer. Block = 512 threads on one 16-row
// q-tile. Waves 0-3 (producers): K loads + MFMA + exp -> swizzled LDS panel;
// their vmcnt FIFO holds ONLY loads. Waves 4-7 (consumers): linear ds_read ->
// coalesced 1KB global stores; their vmcnt FIFO holds ONLY stores and they
// NEVER wait on vmcnt (LDS order via lgkmcnt; raw s_barrier, no vmcnt drain).
// This keeps P-stores streaming like the 6.6 TB/s fill kernel.
__launch_bounds__(512, 4)
__global__ void p_writer_kernel(const float* __restrict__ Q,
                                const short* __restrict__ Kb,
                                const float* __restrict__ Rl,
                                float* __restrict__ P) {
    __shared__ __align__(16) float stage[2][16 * PCOLS];   // 2 x 32 KB panels

    const int tid  = threadIdx.x;
    const int lane = tid & 63;
    const int w    = tid >> 6;                         // 0..7
    const int bh   = blockIdx.y;
    const int qbase = blockIdx.x * 16;
    const int lrow = lane & 15;
    const int lgrp = lane >> 4;
    const float scale = 0.125f;

    const short* Kp = Kb + (size_t)bh * (S_LEN * D_HEAD);
    float* Pb = P + (size_t)bh * S_LEN * S_LEN;

    short8 q0 = {}, q1 = {};
    float rl = 0.f;
    if (w < 4) {
        const float* qr = Q + ((size_t)bh * S_LEN + qbase + lrow) * D_HEAD + lgrp * 8;
        #pragma unroll
        for (int e = 0; e < 8; ++e) q0[e] = f2bf(qr[e]);
        #pragma unroll
        for (int e = 0; e < 8; ++e) q1[e] = f2bf(qr[e + 32]);
        rl = Rl[(size_t)bh * S_LEN + qbase + lrow];
    }

    const int swz = (lrow & 7) << 4;                   // XOR within 128B groups

    for (int p = 0; p <= S_LEN / PCOLS; ++p) {
        if (w < 4) {
            if (p < S_LEN / PCOLS) {
                // produce panel p into stage[p&1]: wave w covers panel cols
                // [w*128, w*128+128) in 4 iterations of 32 columns
                char* stg = (char*)&stage[p & 1][0];
                #pragma unroll
                for (int it = 0; it < 4; ++it) {
                    const int jl = w * 128 + it * 32;  // col within panel
                    const int j0 = p * PCOLS + jl;     // global col (= K row)
                    const short* kr0 = Kp + (size_t)(j0 + lrow) * D_HEAD + lgrp * 8;
                    const short* kr1 = kr0 + 16 * D_HEAD;
                    short8 k00 = *reinterpret_cast<const short8*>(kr0);
                    short8 k01 = *reinterpret_cast<const short8*>(kr0 + 32);
                    short8 k10 = *reinterpret_cast<const short8*>(kr1);
                    short8 k11 = *reinterpret_cast<const short8*>(kr1 + 32);
                    f32x4 c0 = {0.f, 0.f, 0.f, 0.f};
                    f32x4 c1 = {0.f, 0.f, 0.f, 0.f};
                    c0 = __builtin_amdgcn_mfma_f32_16x16x32_bf16(k00, q0, c0, 0, 0, 0);
                    c0 = __builtin_amdgcn_mfma_f32_16x16x32_bf16(k01, q1, c0, 0, 0, 0);
                    c1 = __builtin_amdgcn_mfma_f32_16x16x32_bf16(k10, q0, c1, 0, 0, 0);
                    c1 = __builtin_amdgcn_mfma_f32_16x16x32_bf16(k11, q1, c1, 0, 0, 0);
                    f32x4 p0, p1;
                    #pragma unroll
                    for (int rr = 0; rr < 4; ++rr) {
                        p0[rr] = __expf(c0[rr] * scale) * rl;
                        p1[rr] = __expf(c1[rr] * scale) * rl;
                    }
                    // value(row=lrow, panel col j) at stg[row*2048 + (j*4 ^ swz)]
                    *(f32x4*)(stg + (lrow * 2048 + (((jl + lgrp * 4) << 2) ^ swz))) = p0;
                    *(f32x4*)(stg + (lrow * 2048 + (((jl + 16 + lgrp * 4) << 2) ^ swz))) = p1;
                }
            }
        } else {
            if (p > 0) {
                // drain panel p-1 from stage[(p-1)&1]: wave owns 4 rows,
                // per row two 1KB coalesced stores (un-swizzle on global side)
                const int q = p - 1;
                const char* stg = (const char*)&stage[q & 1][0];
                const int r0 = (w - 4) * 4;
                #pragma unroll
                for (int rr = 0; rr < 4; ++rr) {
                    const int r = r0 + rr;
                    const int rswz = (r & 7) << 4;
                    float* grow = Pb + (size_t)(qbase + r) * S_LEN + q * PCOLS;
                    #pragma unroll
                    for (int h = 0; h < 2; ++h) {
                        const int b = h * 1024 + lane * 16;
                        f32x4 v = *(const f32x4*)(stg + r * 2048 + b);
                        *(f32x4*)((char*)grow + (b ^ rswz)) = v;
                    }
                }
            }
        }
        // phase boundary: order LDS ops only — never drain vmcnt
        asm volatile("s_waitcnt lgkmcnt(0)" ::: "memory");
        __builtin_amdgcn_s_barrier();
        __builtin_amdgcn_sched_barrier(0);
    }
}

extern "C" void kernel_launch(void* const* d_in, const int* in_sizes, int n_in,
                              void* d_out, int out_size, void* d_ws, size_t ws_size,
                              hipStream_t stream) {
    const float* Q = (const float*)d_in[0];
    const float* K = (const float*)d_in[1];
    const float* V = (const float*)d_in[2];
    float* Out = (float*)d_out;
    float* P = Out + (size_t)NELEM;                    // outputs concatenated flat
    short* Kb = (short*)d_ws;                          // 8.4 MB
    short* Vtb = Kb + (size_t)NELEM;                   // 8.4 MB
    float* Rl = (float*)(Vtb + (size_t)NELEM);         // 256 KB (ws >= ~17.1 MB)

    convert_k_kernel<<<NELEM / (256 * 4), 256, 0, stream>>>(K, Kb);
    transpose_v_kernel<<<dim3(S_LEN / 64, NBH), 256, 0, stream>>>(V, Vtb);
    attn_pv_kernel<<<dim3(S_LEN / 64, NBH), 256, 0, stream>>>(Q, Kb, Vtb, Out, Rl);
    p_writer_kernel<<<dim3(S_LEN / 16, NBH), 512, 0, stream>>>(Q, Kb, Rl, P);
}

// Round 8
// 274.472 us; speedup vs baseline: 1.6154x; 1.6154x over previous
//
#include <hip/hip_runtime.h>
#include <hip/hip_bf16.h>
#include <cstdint>
#include <cstddef>

#define S_LEN 2048
#define D_HEAD 64
#define NBH 32                      // B*H = 2*16
#define NELEM 4194304               // NBH * S_LEN * D_HEAD
#define SUP 128                     // columns per store superblock

typedef __attribute__((ext_vector_type(8))) short short8;
typedef __attribute__((ext_vector_type(4))) float f32x4;

__device__ __forceinline__ short f2bf(float f) {
    union { float f; uint32_t u; } v; v.f = f;
    uint32_t u = v.u + 0x7FFFu + ((v.u >> 16) & 1u);   // RNE, inputs finite
    return (short)(u >> 16);
}

__device__ __forceinline__ uint32_t pkbf(float lo, float hi) {
    return ((uint32_t)(uint16_t)f2bf(hi) << 16) | (uint32_t)(uint16_t)f2bf(lo);
}

// K fp32 -> bf16, same layout
__global__ void convert_k_kernel(const float* __restrict__ K, short* __restrict__ Kb) {
    int i = blockIdx.x * 256 + threadIdx.x;
    float4 x = reinterpret_cast<const float4*>(K)[i];
    short4 y;
    y.x = f2bf(x.x); y.y = f2bf(x.y); y.z = f2bf(x.z); y.w = f2bf(x.w);
    reinterpret_cast<short4*>(Kb)[i] = y;
}

// V fp32 [bh][S][D] -> bf16 transposed [bh][D][S]
__global__ void transpose_v_kernel(const float* __restrict__ V, short* __restrict__ Vtb) {
    __shared__ float tile[64][65];
    const int bh = blockIdx.y;
    const int s0 = blockIdx.x * 64;
    const int d = threadIdx.x & 63;
    const int r = threadIdx.x >> 6;
    const float* vp = V + ((size_t)bh * S_LEN + s0) * D_HEAD;
    #pragma unroll
    for (int i = 0; i < 16; ++i) {
        int s = i * 4 + r;
        tile[s][d] = vp[(size_t)s * D_HEAD + d];
    }
    __syncthreads();
    short* op = Vtb + (size_t)bh * (D_HEAD * S_LEN) + s0;
    #pragma unroll
    for (int i = 0; i < 16; ++i) {
        int dd = i * 4 + r;
        op[(size_t)dd * S_LEN + d] = f2bf(tile[d][dd]);
    }
}

// Fused attention. One wave = 32 q-rows (two 16-row subtiles A/B) so every
// K/V fragment load feeds TWO subtiles (2x register reuse -> halves the
// delivered-bytes that R1-R7 suggest is the real bottleneck).
// Swapped QK^T: mfma(A=K, B=Q) -> lane holds scores for q = lane&15 at
// k = (lane>>4)*4 + reg (+16 for the c1 tile).
__launch_bounds__(256, 2)
__global__ void attn_kernel(const float* __restrict__ Q,
                            const short* __restrict__ Kb,
                            const short* __restrict__ Vtb,
                            float* __restrict__ Out,
                            float* __restrict__ P) {
    __shared__ __align__(16) float stage[4][2][16][SUP];   // 64 KB

    const int lane = threadIdx.x & 63;
    const int w    = threadIdx.x >> 6;
    const int bh   = blockIdx.y;
    const int qb   = blockIdx.x * 128 + w * 32;        // wave's 32-row base
    const int lrow = lane & 15;
    const int lgrp = lane >> 4;
    const float scale = 0.125f;                        // 1/sqrt(64)

    // Q fragments for both subtiles (B operand: col = q-row, d = lgrp*8+e)
    short8 qa0A, qa1A, qa0B, qa1B;
    {
        const float* qrA = Q + ((size_t)bh * S_LEN + qb + lrow) * D_HEAD + lgrp * 8;
        const float* qrB = qrA + 16 * D_HEAD;
        #pragma unroll
        for (int e = 0; e < 8; ++e) qa0A[e] = f2bf(qrA[e]);
        #pragma unroll
        for (int e = 0; e < 8; ++e) qa1A[e] = f2bf(qrA[e + 32]);
        #pragma unroll
        for (int e = 0; e < 8; ++e) qa0B[e] = f2bf(qrB[e]);
        #pragma unroll
        for (int e = 0; e < 8; ++e) qa1B[e] = f2bf(qrB[e + 32]);
    }

    const short* Kp = Kb + (size_t)bh * (S_LEN * D_HEAD);
    const short* Vp = Vtb + (size_t)bh * (D_HEAD * S_LEN);

    // bpermute source lanes for the 4x4 word transpose (byte addr = lane*4)
    const int srcA = ((lane & 15) + ((lane >> 4) & 1) * 32) << 2;
    const int srcB = srcA + (16 << 2);
    const bool glow = (lgrp < 2);

    // ---- pass 1: denominators + PV (unnormalized e) for both subtiles ----
    float lA = 0.f, lB = 0.f;
    f32x4 accA[4] = {}, accB[4] = {};
    for (int j0 = 0; j0 < S_LEN; j0 += 32) {
        const short* kr0 = Kp + (size_t)(j0 + lrow) * D_HEAD + lgrp * 8;
        const short* kr1 = kr0 + 16 * D_HEAD;
        short8 k00 = *reinterpret_cast<const short8*>(kr0);
        short8 k01 = *reinterpret_cast<const short8*>(kr0 + 32);
        short8 k10 = *reinterpret_cast<const short8*>(kr1);
        short8 k11 = *reinterpret_cast<const short8*>(kr1 + 32);
        short8 bv0 = *reinterpret_cast<const short8*>(Vp + (size_t)(0 * 16 + lrow) * S_LEN + j0 + lgrp * 8);
        short8 bv1 = *reinterpret_cast<const short8*>(Vp + (size_t)(1 * 16 + lrow) * S_LEN + j0 + lgrp * 8);
        short8 bv2 = *reinterpret_cast<const short8*>(Vp + (size_t)(2 * 16 + lrow) * S_LEN + j0 + lgrp * 8);
        short8 bv3 = *reinterpret_cast<const short8*>(Vp + (size_t)(3 * 16 + lrow) * S_LEN + j0 + lgrp * 8);

        // ---- subtile A ----
        {
            f32x4 c0 = {0.f, 0.f, 0.f, 0.f};
            f32x4 c1 = {0.f, 0.f, 0.f, 0.f};
            c0 = __builtin_amdgcn_mfma_f32_16x16x32_bf16(k00, qa0A, c0, 0, 0, 0);
            c0 = __builtin_amdgcn_mfma_f32_16x16x32_bf16(k01, qa1A, c0, 0, 0, 0);
            c1 = __builtin_amdgcn_mfma_f32_16x16x32_bf16(k10, qa0A, c1, 0, 0, 0);
            c1 = __builtin_amdgcn_mfma_f32_16x16x32_bf16(k11, qa1A, c1, 0, 0, 0);
            float e0[4], e1[4];
            #pragma unroll
            for (int rr = 0; rr < 4; ++rr) {
                e0[rr] = __expf(c0[rr] * scale);
                e1[rr] = __expf(c1[rr] * scale);
                lA += e0[rr] + e1[rr];
            }
            int w00 = (int)pkbf(e0[0], e0[1]);
            int w01 = (int)pkbf(e0[2], e0[3]);
            int w10 = (int)pkbf(e1[0], e1[1]);
            int w11 = (int)pkbf(e1[2], e1[3]);
            int t0 = __builtin_amdgcn_ds_bpermute(srcA, w00);
            int t1 = __builtin_amdgcn_ds_bpermute(srcA, w01);
            int t2 = __builtin_amdgcn_ds_bpermute(srcB, w00);
            int t3 = __builtin_amdgcn_ds_bpermute(srcB, w01);
            int u0 = __builtin_amdgcn_ds_bpermute(srcA, w10);
            int u1 = __builtin_amdgcn_ds_bpermute(srcA, w11);
            int u2 = __builtin_amdgcn_ds_bpermute(srcB, w10);
            int u3 = __builtin_amdgcn_ds_bpermute(srcB, w11);
            union { short8 s8; int wd[4]; } fr;
            fr.wd[0] = glow ? t0 : u0;
            fr.wd[1] = glow ? t1 : u1;
            fr.wd[2] = glow ? t2 : u2;
            fr.wd[3] = glow ? t3 : u3;
            accA[0] = __builtin_amdgcn_mfma_f32_16x16x32_bf16(fr.s8, bv0, accA[0], 0, 0, 0);
            accA[1] = __builtin_amdgcn_mfma_f32_16x16x32_bf16(fr.s8, bv1, accA[1], 0, 0, 0);
            accA[2] = __builtin_amdgcn_mfma_f32_16x16x32_bf16(fr.s8, bv2, accA[2], 0, 0, 0);
            accA[3] = __builtin_amdgcn_mfma_f32_16x16x32_bf16(fr.s8, bv3, accA[3], 0, 0, 0);
        }
        // ---- subtile B (reuses k??/bv? registers) ----
        {
            f32x4 c0 = {0.f, 0.f, 0.f, 0.f};
            f32x4 c1 = {0.f, 0.f, 0.f, 0.f};
            c0 = __builtin_amdgcn_mfma_f32_16x16x32_bf16(k00, qa0B, c0, 0, 0, 0);
            c0 = __builtin_amdgcn_mfma_f32_16x16x32_bf16(k01, qa1B, c0, 0, 0, 0);
            c1 = __builtin_amdgcn_mfma_f32_16x16x32_bf16(k10, qa0B, c1, 0, 0, 0);
            c1 = __builtin_amdgcn_mfma_f32_16x16x32_bf16(k11, qa1B, c1, 0, 0, 0);
            float e0[4], e1[4];
            #pragma unroll
            for (int rr = 0; rr < 4; ++rr) {
                e0[rr] = __expf(c0[rr] * scale);
                e1[rr] = __expf(c1[rr] * scale);
                lB += e0[rr] + e1[rr];
            }
            int w00 = (int)pkbf(e0[0], e0[1]);
            int w01 = (int)pkbf(e0[2], e0[3]);
            int w10 = (int)pkbf(e1[0], e1[1]);
            int w11 = (int)pkbf(e1[2], e1[3]);
            int t0 = __builtin_amdgcn_ds_bpermute(srcA, w00);
            int t1 = __builtin_amdgcn_ds_bpermute(srcA, w01);
            int t2 = __builtin_amdgcn_ds_bpermute(srcB, w00);
            int t3 = __builtin_amdgcn_ds_bpermute(srcB, w01);
            int u0 = __builtin_amdgcn_ds_bpermute(srcA, w10);
            int u1 = __builtin_amdgcn_ds_bpermute(srcA, w11);
            int u2 = __builtin_amdgcn_ds_bpermute(srcB, w10);
            int u3 = __builtin_amdgcn_ds_bpermute(srcB, w11);
            union { short8 s8; int wd[4]; } fr;
            fr.wd[0] = glow ? t0 : u0;
            fr.wd[1] = glow ? t1 : u1;
            fr.wd[2] = glow ? t2 : u2;
            fr.wd[3] = glow ? t3 : u3;
            accB[0] = __builtin_amdgcn_mfma_f32_16x16x32_bf16(fr.s8, bv0, accB[0], 0, 0, 0);
            accB[1] = __builtin_amdgcn_mfma_f32_16x16x32_bf16(fr.s8, bv1, accB[1], 0, 0, 0);
            accB[2] = __builtin_amdgcn_mfma_f32_16x16x32_bf16(fr.s8, bv2, accB[2], 0, 0, 0);
            accB[3] = __builtin_amdgcn_mfma_f32_16x16x32_bf16(fr.s8, bv3, accB[3], 0, 0, 0);
        }
    }
    lA += __shfl_xor(lA, 16);  lA += __shfl_xor(lA, 32);
    lB += __shfl_xor(lB, 16);  lB += __shfl_xor(lB, 32);
    const float rlA = 1.0f / lA;                       // denom for q = qb+lrow
    const float rlB = 1.0f / lB;                       // denom for q = qb+16+lrow

    // ---- pass 2: P stream; each K load feeds both subtiles ----
    char* stgA = (char*)&stage[w][0][0][0];
    char* stgB = (char*)&stage[w][1][0][0];
    const int swz = (lrow & 7) << 4;
    float* Pb = P + (size_t)bh * S_LEN * S_LEN;

    for (int sup = 0; sup < S_LEN; sup += SUP) {
        #pragma unroll
        for (int jj = 0; jj < SUP / 32; ++jj) {
            const int j0 = sup + jj * 32;
            const short* kr0 = Kp + (size_t)(j0 + lrow) * D_HEAD + lgrp * 8;
            const short* kr1 = kr0 + 16 * D_HEAD;
            short8 k00 = *reinterpret_cast<const short8*>(kr0);
            short8 k01 = *reinterpret_cast<const short8*>(kr0 + 32);
            short8 k10 = *reinterpret_cast<const short8*>(kr1);
            short8 k11 = *reinterpret_cast<const short8*>(kr1 + 32);
            const int o0 = (lrow * 512 + ((jj * 32 + lgrp * 4) << 2)) ^ swz;
            const int o1 = (lrow * 512 + ((jj * 32 + 16 + lgrp * 4) << 2)) ^ swz;
            {
                f32x4 c0 = {0.f, 0.f, 0.f, 0.f};
                f32x4 c1 = {0.f, 0.f, 0.f, 0.f};
                c0 = __builtin_amdgcn_mfma_f32_16x16x32_bf16(k00, qa0A, c0, 0, 0, 0);
                c0 = __builtin_amdgcn_mfma_f32_16x16x32_bf16(k01, qa1A, c0, 0, 0, 0);
                c1 = __builtin_amdgcn_mfma_f32_16x16x32_bf16(k10, qa0A, c1, 0, 0, 0);
                c1 = __builtin_amdgcn_mfma_f32_16x16x32_bf16(k11, qa1A, c1, 0, 0, 0);
                f32x4 p0, p1;
                #pragma unroll
                for (int rr = 0; rr < 4; ++rr) {
                    p0[rr] = __expf(c0[rr] * scale) * rlA;
                    p1[rr] = __expf(c1[rr] * scale) * rlA;
                }
                *(f32x4*)(stgA + o0) = p0;
                *(f32x4*)(stgA + o1) = p1;
            }
            {
                f32x4 c0 = {0.f, 0.f, 0.f, 0.f};
                f32x4 c1 = {0.f, 0.f, 0.f, 0.f};
                c0 = __builtin_amdgcn_mfma_f32_16x16x32_bf16(k00, qa0B, c0, 0, 0, 0);
                c0 = __builtin_amdgcn_mfma_f32_16x16x32_bf16(k01, qa1B, c0, 0, 0, 0);
                c1 = __builtin_amdgcn_mfma_f32_16x16x32_bf16(k10, qa0B, c1, 0, 0, 0);
                c1 = __builtin_amdgcn_mfma_f32_16x16x32_bf16(k11, qa1B, c1, 0, 0, 0);
                f32x4 p0, p1;
                #pragma unroll
                for (int rr = 0; rr < 4; ++rr) {
                    p0[rr] = __expf(c0[rr] * scale) * rlB;
                    p1[rr] = __expf(c1[rr] * scale) * rlB;
                }
                *(f32x4*)(stgB + o0) = p0;
                *(f32x4*)(stgB + o1) = p1;
            }
        }

        asm volatile("s_waitcnt lgkmcnt(0)" ::: "memory");
        // burst store: 2 rows x 512B per instruction, per subtile
        #pragma unroll
        for (int rb = 0; rb < 8; ++rb) {
            const int r = rb * 2 + (lane >> 5);
            const int c = lane & 31;
            f32x4 pv = *(const f32x4*)(stgA + ((r * 512 + c * 16) ^ ((r & 7) << 4)));
            *(f32x4*)(Pb + (size_t)(qb + r) * S_LEN + sup + c * 4) = pv;
        }
        #pragma unroll
        for (int rb = 0; rb < 8; ++rb) {
            const int r = rb * 2 + (lane >> 5);
            const int c = lane & 31;
            f32x4 pv = *(const f32x4*)(stgB + ((r * 512 + c * 16) ^ ((r & 7) << 4)));
            *(f32x4*)(Pb + (size_t)(qb + 16 + r) * S_LEN + sup + c * 4) = pv;
        }
        // reads above must land before next sup's stage writes
        asm volatile("s_waitcnt lgkmcnt(0)" ::: "memory");
    }

    // ---- epilogue: Out rows for both subtiles ----
    float rloA[4], rloB[4];
    #pragma unroll
    for (int rr = 0; rr < 4; ++rr) {
        rloA[rr] = __shfl(rlA, lgrp * 4 + rr);
        rloB[rr] = __shfl(rlB, lgrp * 4 + rr);
    }
    float* obA = Out + ((size_t)bh * S_LEN + qb + lgrp * 4) * D_HEAD + lrow;
    float* obB = obA + (size_t)16 * D_HEAD;
    #pragma unroll
    for (int vt = 0; vt < 4; ++vt) {
        #pragma unroll
        for (int rr = 0; rr < 4; ++rr) {
            obA[(size_t)rr * D_HEAD + vt * 16] = accA[vt][rr] * rloA[rr];
            obB[(size_t)rr * D_HEAD + vt * 16] = accB[vt][rr] * rloB[rr];
        }
    }
}

extern "C" void kernel_launch(void* const* d_in, const int* in_sizes, int n_in,
                              void* d_out, int out_size, void* d_ws, size_t ws_size,
                              hipStream_t stream) {
    const float* Q = (const float*)d_in[0];
    const float* K = (const float*)d_in[1];
    const float* V = (const float*)d_in[2];
    float* Out = (float*)d_out;
    float* P = Out + (size_t)NELEM;                    // outputs concatenated flat
    short* Kb = (short*)d_ws;                          // 8.4 MB
    short* Vtb = Kb + (size_t)NELEM;                   // 8.4 MB (needs ws >= 16.8 MB)

    convert_k_kernel<<<NELEM / (256 * 4), 256, 0, stream>>>(K, Kb);
    transpose_v_kernel<<<dim3(S_LEN / 64, NBH), 256, 0, stream>>>(V, Vtb);
    attn_kernel<<<dim3(S_LEN / 128, NBH), 256, 0, stream>>>(Q, Kb, Vtb, Out, P);
}

// Round 9
// 201.694 us; speedup vs baseline: 2.1983x; 1.3608x over previous
//
#include <hip/hip_runtime.h>
#include <hip/hip_bf16.h>
#include <cstdint>
#include <cstddef>

#define S_LEN 2048
#define D_HEAD 64
#define NBH 32                      // B*H = 2*16
#define NELEM 4194304               // NBH * S_LEN * D_HEAD
#define SUP 128                     // columns per store superblock

typedef __attribute__((ext_vector_type(8))) short short8;
typedef __attribute__((ext_vector_type(4))) float f32x4;

__device__ __forceinline__ short f2bf(float f) {
    union { float f; uint32_t u; } v; v.f = f;
    uint32_t u = v.u + 0x7FFFu + ((v.u >> 16) & 1u);   // RNE, inputs finite
    return (short)(u >> 16);
}

__device__ __forceinline__ uint32_t pkbf(float lo, float hi) {
    return ((uint32_t)(uint16_t)f2bf(hi) << 16) | (uint32_t)(uint16_t)f2bf(lo);
}

// K fp32 -> fragment-major bf16:
// Kf slot s = ((bh*128 + g)*2 + p)*64 + l holds K[bh][g*16 + (l&15)][p*32 + (l>>4)*8 + e]
// so the attn kernel's K loads are lane-linear (base + lane*16B, 1KB dense).
__global__ void convert_kf_kernel(const float* __restrict__ K, short* __restrict__ Kf) {
    const int s = blockIdx.x * 256 + threadIdx.x;      // 524288 slots total
    const int l = s & 63;
    const int p = (s >> 6) & 1;
    const int g = (s >> 7) & 127;
    const int bh = s >> 14;
    const float* src = K + ((size_t)bh * S_LEN + g * 16 + (l & 15)) * D_HEAD
                         + p * 32 + (l >> 4) * 8;
    short8 y;
    #pragma unroll
    for (int e = 0; e < 8; ++e) y[e] = f2bf(src[e]);
    *reinterpret_cast<short8*>(Kf + (size_t)s * 8) = y;
}

// V fp32 [bh][S][D] -> fragment-major bf16:
// Vf slot s = ((bh*64 + t)*4 + vt)*64 + l holds V[bh][t*32 + (l>>4)*8 + e][vt*16 + (l&15)]
__global__ void transpose_vf_kernel(const float* __restrict__ V, short* __restrict__ Vf) {
    __shared__ float tile[64][65];
    const int bh = blockIdx.y;
    const int s0 = blockIdx.x * 64;
    const int d = threadIdx.x & 63;
    const int r = threadIdx.x >> 6;
    const float* vp = V + ((size_t)bh * S_LEN + s0) * D_HEAD;
    #pragma unroll
    for (int i = 0; i < 16; ++i) {
        int srow = i * 4 + r;
        tile[srow][d] = vp[(size_t)srow * D_HEAD + d];
    }
    __syncthreads();
    #pragma unroll
    for (int h = 0; h < 2; ++h) {
        const int sl = h * 256 + threadIdx.x;          // 512 slots per block
        const int ti = sl >> 8;                        // j-subtile 0..1
        const int vt = (sl >> 6) & 3;
        const int l  = sl & 63;
        const int lrow = l & 15, lgrp = l >> 4;
        short8 y;
        #pragma unroll
        for (int e = 0; e < 8; ++e)
            y[e] = f2bf(tile[ti * 32 + lgrp * 8 + e][vt * 16 + lrow]);
        *reinterpret_cast<short8*>(
            Vf + ((((size_t)bh * 64 + (s0 >> 5) + ti) * 4 + vt) * 64 + l) * 8) = y;
    }
}

// Fused attention (R8 structure: wave = 32 q-rows, 2 subtiles sharing K/V regs)
// with fragment-major K/V so every hot-loop load is fully coalesced.
__launch_bounds__(256, 2)
__global__ void attn_kernel(const float* __restrict__ Q,
                            const short* __restrict__ Kf,
                            const short* __restrict__ Vf,
                            float* __restrict__ Out,
                            float* __restrict__ P) {
    __shared__ __align__(16) float stage[4][2][16][SUP];   // 64 KB

    const int lane = threadIdx.x & 63;
    const int w    = threadIdx.x >> 6;
    const int bh   = blockIdx.y;
    const int qb   = blockIdx.x * 128 + w * 32;        // wave's 32-row base
    const int lrow = lane & 15;
    const int lgrp = lane >> 4;
    const float scale = 0.125f;                        // 1/sqrt(64)

    short8 qa0A, qa1A, qa0B, qa1B;
    {
        const float* qrA = Q + ((size_t)bh * S_LEN + qb + lrow) * D_HEAD + lgrp * 8;
        const float* qrB = qrA + 16 * D_HEAD;
        #pragma unroll
        for (int e = 0; e < 8; ++e) qa0A[e] = f2bf(qrA[e]);
        #pragma unroll
        for (int e = 0; e < 8; ++e) qa1A[e] = f2bf(qrA[e + 32]);
        #pragma unroll
        for (int e = 0; e < 8; ++e) qa0B[e] = f2bf(qrB[e]);
        #pragma unroll
        for (int e = 0; e < 8; ++e) qa1B[e] = f2bf(qrB[e + 32]);
    }

    const short* Kp = Kf + (size_t)bh * (S_LEN * D_HEAD);   // 1024 elems / 16-row group
    const short* Vp = Vf + (size_t)bh * (S_LEN * D_HEAD);   // 2048 elems / 32-col tile
    const int lofs = lane * 8;

    const int srcA = ((lane & 15) + ((lane >> 4) & 1) * 32) << 2;
    const int srcB = srcA + (16 << 2);
    const bool glow = (lgrp < 2);

    // ---- pass 1: denominators + PV (unnormalized e) for both subtiles ----
    float lA = 0.f, lB = 0.f;
    f32x4 accA[4] = {}, accB[4] = {};
    for (int j0 = 0; j0 < S_LEN; j0 += 32) {
        const short* kg = Kp + (size_t)(j0 >> 4) * 1024;
        short8 k00 = *reinterpret_cast<const short8*>(kg + lofs);
        short8 k01 = *reinterpret_cast<const short8*>(kg + 512 + lofs);
        short8 k10 = *reinterpret_cast<const short8*>(kg + 1024 + lofs);
        short8 k11 = *reinterpret_cast<const short8*>(kg + 1536 + lofs);
        const short* vg = Vp + (size_t)(j0 >> 5) * 2048;
        short8 bv0 = *reinterpret_cast<const short8*>(vg + lofs);
        short8 bv1 = *reinterpret_cast<const short8*>(vg + 512 + lofs);
        short8 bv2 = *reinterpret_cast<const short8*>(vg + 1024 + lofs);
        short8 bv3 = *reinterpret_cast<const short8*>(vg + 1536 + lofs);

        // ---- subtile A ----
        {
            f32x4 c0 = {0.f, 0.f, 0.f, 0.f};
            f32x4 c1 = {0.f, 0.f, 0.f, 0.f};
            c0 = __builtin_amdgcn_mfma_f32_16x16x32_bf16(k00, qa0A, c0, 0, 0, 0);
            c0 = __builtin_amdgcn_mfma_f32_16x16x32_bf16(k01, qa1A, c0, 0, 0, 0);
            c1 = __builtin_amdgcn_mfma_f32_16x16x32_bf16(k10, qa0A, c1, 0, 0, 0);
            c1 = __builtin_amdgcn_mfma_f32_16x16x32_bf16(k11, qa1A, c1, 0, 0, 0);
            float e0[4], e1[4];
            #pragma unroll
            for (int rr = 0; rr < 4; ++rr) {
                e0[rr] = __expf(c0[rr] * scale);
                e1[rr] = __expf(c1[rr] * scale);
                lA += e0[rr] + e1[rr];
            }
            int w00 = (int)pkbf(e0[0], e0[1]);
            int w01 = (int)pkbf(e0[2], e0[3]);
            int w10 = (int)pkbf(e1[0], e1[1]);
            int w11 = (int)pkbf(e1[2], e1[3]);
            int t0 = __builtin_amdgcn_ds_bpermute(srcA, w00);
            int t1 = __builtin_amdgcn_ds_bpermute(srcA, w01);
            int t2 = __builtin_amdgcn_ds_bpermute(srcB, w00);
            int t3 = __builtin_amdgcn_ds_bpermute(srcB, w01);
            int u0 = __builtin_amdgcn_ds_bpermute(srcA, w10);
            int u1 = __builtin_amdgcn_ds_bpermute(srcA, w11);
            int u2 = __builtin_amdgcn_ds_bpermute(srcB, w10);
            int u3 = __builtin_amdgcn_ds_bpermute(srcB, w11);
            union { short8 s8; int wd[4]; } fr;
            fr.wd[0] = glow ? t0 : u0;
            fr.wd[1] = glow ? t1 : u1;
            fr.wd[2] = glow ? t2 : u2;
            fr.wd[3] = glow ? t3 : u3;
            accA[0] = __builtin_amdgcn_mfma_f32_16x16x32_bf16(fr.s8, bv0, accA[0], 0, 0, 0);
            accA[1] = __builtin_amdgcn_mfma_f32_16x16x32_bf16(fr.s8, bv1, accA[1], 0, 0, 0);
            accA[2] = __builtin_amdgcn_mfma_f32_16x16x32_bf16(fr.s8, bv2, accA[2], 0, 0, 0);
            accA[3] = __builtin_amdgcn_mfma_f32_16x16x32_bf16(fr.s8, bv3, accA[3], 0, 0, 0);
        }
        // ---- subtile B (reuses k??/bv? registers) ----
        {
            f32x4 c0 = {0.f, 0.f, 0.f, 0.f};
            f32x4 c1 = {0.f, 0.f, 0.f, 0.f};
            c0 = __builtin_amdgcn_mfma_f32_16x16x32_bf16(k00, qa0B, c0, 0, 0, 0);
            c0 = __builtin_amdgcn_mfma_f32_16x16x32_bf16(k01, qa1B, c0, 0, 0, 0);
            c1 = __builtin_amdgcn_mfma_f32_16x16x32_bf16(k10, qa0B, c1, 0, 0, 0);
            c1 = __builtin_amdgcn_mfma_f32_16x16x32_bf16(k11, qa1B, c1, 0, 0, 0);
            float e0[4], e1[4];
            #pragma unroll
            for (int rr = 0; rr < 4; ++rr) {
                e0[rr] = __expf(c0[rr] * scale);
                e1[rr] = __expf(c1[rr] * scale);
                lB += e0[rr] + e1[rr];
            }
            int w00 = (int)pkbf(e0[0], e0[1]);
            int w01 = (int)pkbf(e0[2], e0[3]);
            int w10 = (int)pkbf(e1[0], e1[1]);
            int w11 = (int)pkbf(e1[2], e1[3]);
            int t0 = __builtin_amdgcn_ds_bpermute(srcA, w00);
            int t1 = __builtin_amdgcn_ds_bpermute(srcA, w01);
            int t2 = __builtin_amdgcn_ds_bpermute(srcB, w00);
            int t3 = __builtin_amdgcn_ds_bpermute(srcB, w01);
            int u0 = __builtin_amdgcn_ds_bpermute(srcA, w10);
            int u1 = __builtin_amdgcn_ds_bpermute(srcA, w11);
            int u2 = __builtin_amdgcn_ds_bpermute(srcB, w10);
            int u3 = __builtin_amdgcn_ds_bpermute(srcB, w11);
            union { short8 s8; int wd[4]; } fr;
            fr.wd[0] = glow ? t0 : u0;
            fr.wd[1] = glow ? t1 : u1;
            fr.wd[2] = glow ? t2 : u2;
            fr.wd[3] = glow ? t3 : u3;
            accB[0] = __builtin_amdgcn_mfma_f32_16x16x32_bf16(fr.s8, bv0, accB[0], 0, 0, 0);
            accB[1] = __builtin_amdgcn_mfma_f32_16x16x32_bf16(fr.s8, bv1, accB[1], 0, 0, 0);
            accB[2] = __builtin_amdgcn_mfma_f32_16x16x32_bf16(fr.s8, bv2, accB[2], 0, 0, 0);
            accB[3] = __builtin_amdgcn_mfma_f32_16x16x32_bf16(fr.s8, bv3, accB[3], 0, 0, 0);
        }
    }
    lA += __shfl_xor(lA, 16);  lA += __shfl_xor(lA, 32);
    lB += __shfl_xor(lB, 16);  lB += __shfl_xor(lB, 32);
    const float rlA = 1.0f / lA;                       // denom for q = qb+lrow
    const float rlB = 1.0f / lB;                       // denom for q = qb+16+lrow

    // ---- pass 2: P stream; each K load feeds both subtiles ----
    char* stgA = (char*)&stage[w][0][0][0];
    char* stgB = (char*)&stage[w][1][0][0];
    const int swz = (lrow & 7) << 4;
    float* Pb = P + (size_t)bh * S_LEN * S_LEN;

    for (int sup = 0; sup < S_LEN; sup += SUP) {
        #pragma unroll
        for (int jj = 0; jj < SUP / 32; ++jj) {
            const int j0 = sup + jj * 32;
            const short* kg = Kp + (size_t)(j0 >> 4) * 1024;
            short8 k00 = *reinterpret_cast<const short8*>(kg + lofs);
            short8 k01 = *reinterpret_cast<const short8*>(kg + 512 + lofs);
            short8 k10 = *reinterpret_cast<const short8*>(kg + 1024 + lofs);
            short8 k11 = *reinterpret_cast<const short8*>(kg + 1536 + lofs);
            const int o0 = (lrow * 512 + ((jj * 32 + lgrp * 4) << 2)) ^ swz;
            const int o1 = (lrow * 512 + ((jj * 32 + 16 + lgrp * 4) << 2)) ^ swz;
            {
                f32x4 c0 = {0.f, 0.f, 0.f, 0.f};
                f32x4 c1 = {0.f, 0.f, 0.f, 0.f};
                c0 = __builtin_amdgcn_mfma_f32_16x16x32_bf16(k00, qa0A, c0, 0, 0, 0);
                c0 = __builtin_amdgcn_mfma_f32_16x16x32_bf16(k01, qa1A, c0, 0, 0, 0);
                c1 = __builtin_amdgcn_mfma_f32_16x16x32_bf16(k10, qa0A, c1, 0, 0, 0);
                c1 = __builtin_amdgcn_mfma_f32_16x16x32_bf16(k11, qa1A, c1, 0, 0, 0);
                f32x4 p0, p1;
                #pragma unroll
                for (int rr = 0; rr < 4; ++rr) {
                    p0[rr] = __expf(c0[rr] * scale) * rlA;
                    p1[rr] = __expf(c1[rr] * scale) * rlA;
                }
                *(f32x4*)(stgA + o0) = p0;
                *(f32x4*)(stgA + o1) = p1;
            }
            {
                f32x4 c0 = {0.f, 0.f, 0.f, 0.f};
                f32x4 c1 = {0.f, 0.f, 0.f, 0.f};
                c0 = __builtin_amdgcn_mfma_f32_16x16x32_bf16(k00, qa0B, c0, 0, 0, 0);
                c0 = __builtin_amdgcn_mfma_f32_16x16x32_bf16(k01, qa1B, c0, 0, 0, 0);
                c1 = __builtin_amdgcn_mfma_f32_16x16x32_bf16(k10, qa0B, c1, 0, 0, 0);
                c1 = __builtin_amdgcn_mfma_f32_16x16x32_bf16(k11, qa1B, c1, 0, 0, 0);
                f32x4 p0, p1;
                #pragma unroll
                for (int rr = 0; rr < 4; ++rr) {
                    p0[rr] = __expf(c0[rr] * scale) * rlB;
                    p1[rr] = __expf(c1[rr] * scale) * rlB;
                }
                *(f32x4*)(stgB + o0) = p0;
                *(f32x4*)(stgB + o1) = p1;
            }
        }

        asm volatile("s_waitcnt lgkmcnt(0)" ::: "memory");
        #pragma unroll
        for (int rb = 0; rb < 8; ++rb) {
            const int r = rb * 2 + (lane >> 5);
            const int c = lane & 31;
            f32x4 pv = *(const f32x4*)(stgA + ((r * 512 + c * 16) ^ ((r & 7) << 4)));
            *(f32x4*)(Pb + (size_t)(qb + r) * S_LEN + sup + c * 4) = pv;
        }
        #pragma unroll
        for (int rb = 0; rb < 8; ++rb) {
            const int r = rb * 2 + (lane >> 5);
            const int c = lane & 31;
            f32x4 pv = *(const f32x4*)(stgB + ((r * 512 + c * 16) ^ ((r & 7) << 4)));
            *(f32x4*)(Pb + (size_t)(qb + 16 + r) * S_LEN + sup + c * 4) = pv;
        }
        asm volatile("s_waitcnt lgkmcnt(0)" ::: "memory");
    }

    // ---- epilogue: Out rows for both subtiles ----
    float rloA[4], rloB[4];
    #pragma unroll
    for (int rr = 0; rr < 4; ++rr) {
        rloA[rr] = __shfl(rlA, lgrp * 4 + rr);
        rloB[rr] = __shfl(rlB, lgrp * 4 + rr);
    }
    float* obA = Out + ((size_t)bh * S_LEN + qb + lgrp * 4) * D_HEAD + lrow;
    float* obB = obA + (size_t)16 * D_HEAD;
    #pragma unroll
    for (int vt = 0; vt < 4; ++vt) {
        #pragma unroll
        for (int rr = 0; rr < 4; ++rr) {
            obA[(size_t)rr * D_HEAD + vt * 16] = accA[vt][rr] * rloA[rr];
            obB[(size_t)rr * D_HEAD + vt * 16] = accB[vt][rr] * rloB[rr];
        }
    }
}

extern "C" void kernel_launch(void* const* d_in, const int* in_sizes, int n_in,
                              void* d_out, int out_size, void* d_ws, size_t ws_size,
                              hipStream_t stream) {
    const float* Q = (const float*)d_in[0];
    const float* K = (const float*)d_in[1];
    const float* V = (const float*)d_in[2];
    float* Out = (float*)d_out;
    float* P = Out + (size_t)NELEM;                    // outputs concatenated flat
    short* Kf = (short*)d_ws;                          // 8.4 MB
    short* Vf = Kf + (size_t)NELEM;                    // 8.4 MB (needs ws >= 16.8 MB)

    convert_kf_kernel<<<NELEM / (256 * 8), 256, 0, stream>>>(K, Kf);
    transpose_vf_kernel<<<dim3(S_LEN / 64, NBH), 256, 0, stream>>>(V, Vf);
    attn_kernel<<<dim3(S_LEN / 128, NBH), 256, 0, stream>>>(Q, Kf, Vf, Out, P);
}

// Round 11
// 187.476 us; speedup vs baseline: 2.3650x; 1.0758x over previous
//
#include <hip/hip_runtime.h>
#include <hip/hip_bf16.h>
#include <cstdint>
#include <cstddef>

#define S_LEN 2048
#define D_HEAD 64
#define NBH 32                      // B*H = 2*16
#define NELEM 4194304               // NBH * S_LEN * D_HEAD
#define SUP 128                     // columns per store superblock

typedef __attribute__((ext_vector_type(8))) short short8;
typedef __attribute__((ext_vector_type(4))) float f32x4;

__device__ __forceinline__ short f2bf(float f) {
    union { float f; uint32_t u; } v; v.f = f;
    uint32_t u = v.u + 0x7FFFu + ((v.u >> 16) & 1u);   // RNE, inputs finite
    return (short)(u >> 16);
}

__device__ __forceinline__ uint32_t pkbf(float lo, float hi) {
    return ((uint32_t)(uint16_t)f2bf(hi) << 16) | (uint32_t)(uint16_t)f2bf(lo);
}

// K fp32 -> fragment-major bf16:
// Kf slot s = ((bh*128 + g)*2 + p)*64 + l holds K[bh][g*16 + (l&15)][p*32 + (l>>4)*8 + e]
__global__ void convert_kf_kernel(const float* __restrict__ K, short* __restrict__ Kf) {
    const int s = blockIdx.x * 256 + threadIdx.x;      // 524288 slots total
    const int l = s & 63;
    const int p = (s >> 6) & 1;
    const int g = (s >> 7) & 127;
    const int bh = s >> 14;
    const float* src = K + ((size_t)bh * S_LEN + g * 16 + (l & 15)) * D_HEAD
                         + p * 32 + (l >> 4) * 8;
    short8 y;
    #pragma unroll
    for (int e = 0; e < 8; ++e) y[e] = f2bf(src[e]);
    *reinterpret_cast<short8*>(Kf + (size_t)s * 8) = y;
}

// V fp32 [bh][S][D] -> fragment-major bf16:
// Vf slot s = ((bh*64 + t)*4 + vt)*64 + l holds V[bh][t*32 + (l>>4)*8 + e][vt*16 + (l&15)]
__global__ void transpose_vf_kernel(const float* __restrict__ V, short* __restrict__ Vf) {
    __shared__ float tile[64][65];
    const int bh = blockIdx.y;
    const int s0 = blockIdx.x * 64;
    const int d = threadIdx.x & 63;
    const int r = threadIdx.x >> 6;
    const float* vp = V + ((size_t)bh * S_LEN + s0) * D_HEAD;
    #pragma unroll
    for (int i = 0; i < 16; ++i) {
        int srow = i * 4 + r;
        tile[srow][d] = vp[(size_t)srow * D_HEAD + d];
    }
    __syncthreads();
    #pragma unroll
    for (int h = 0; h < 2; ++h) {
        const int sl = h * 256 + threadIdx.x;          // 512 slots per block
        const int ti = sl >> 8;                        // j-subtile 0..1
        const int vt = (sl >> 6) & 3;
        const int l  = sl & 63;
        const int lrow = l & 15, lgrp = l >> 4;
        short8 y;
        #pragma unroll
        for (int e = 0; e < 8; ++e)
            y[e] = f2bf(tile[ti * 32 + lgrp * 8 + e][vt * 16 + lrow]);
        *reinterpret_cast<short8*>(
            Vf + ((((size_t)bh * 64 + (s0 >> 5) + ti) * 4 + vt) * 64 + l) * 8) = y;
    }
}

// Fused attention (R9 structure, verified): wave = 32 q-rows (2 subtiles
// sharing K/V registers), fragment-major K/V loads, LDS-staged burst P stores.
// NEW: XCD-aware block swizzle — 512 blocks round-robin XCDs by dispatch id,
// so map b%8 -> a contiguous 4-bh slice per XCD: per-XCD K/V working set
// 2.1MB <= 4MB L2 (was 16.8MB thrashing; K/V re-reads then hit LLC only).
__launch_bounds__(256, 2)
__global__ void attn_kernel(const float* __restrict__ Q,
                            const short* __restrict__ Kf,
                            const short* __restrict__ Vf,
                            float* __restrict__ Out,
                            float* __restrict__ P) {
    __shared__ __align__(16) float stage[4][2][16][SUP];   // 64 KB

    const int lane = threadIdx.x & 63;
    const int w    = threadIdx.x >> 6;
    // XCD swizzle: b = dispatch-linear id; swz bijective on [0,512)
    const int b    = blockIdx.y * 16 + blockIdx.x;
    const int swzb = (b & 7) * 64 + (b >> 3);
    const int bx   = swzb & 15;
    const int bh   = swzb >> 4;
    const int qb   = bx * 128 + w * 32;                // wave's 32-row base
    const int lrow = lane & 15;
    const int lgrp = lane >> 4;
    const float scale = 0.125f;                        // 1/sqrt(64)

    short8 qa0A, qa1A, qa0B, qa1B;
    {
        const float* qrA = Q + ((size_t)bh * S_LEN + qb + lrow) * D_HEAD + lgrp * 8;
        const float* qrB = qrA + 16 * D_HEAD;
        #pragma unroll
        for (int e = 0; e < 8; ++e) qa0A[e] = f2bf(qrA[e]);
        #pragma unroll
        for (int e = 0; e < 8; ++e) qa1A[e] = f2bf(qrA[e + 32]);
        #pragma unroll
        for (int e = 0; e < 8; ++e) qa0B[e] = f2bf(qrB[e]);
        #pragma unroll
        for (int e = 0; e < 8; ++e) qa1B[e] = f2bf(qrB[e + 32]);
    }

    const short* Kp = Kf + (size_t)bh * (S_LEN * D_HEAD);
    const short* Vp = Vf + (size_t)bh * (S_LEN * D_HEAD);
    const int lofs = lane * 8;

    const int srcA = ((lane & 15) + ((lane >> 4) & 1) * 32) << 2;
    const int srcB = srcA + (16 << 2);
    const bool glow = (lgrp < 2);

    // ---- pass 1: denominators + PV (unnormalized e) for both subtiles ----
    float lA = 0.f, lB = 0.f;
    f32x4 accA[4] = {}, accB[4] = {};
    for (int j0 = 0; j0 < S_LEN; j0 += 32) {
        const short* kg = Kp + (size_t)(j0 >> 4) * 1024;
        short8 k00 = *reinterpret_cast<const short8*>(kg + lofs);
        short8 k01 = *reinterpret_cast<const short8*>(kg + 512 + lofs);
        short8 k10 = *reinterpret_cast<const short8*>(kg + 1024 + lofs);
        short8 k11 = *reinterpret_cast<const short8*>(kg + 1536 + lofs);
        const short* vg = Vp + (size_t)(j0 >> 5) * 2048;
        short8 bv0 = *reinterpret_cast<const short8*>(vg + lofs);
        short8 bv1 = *reinterpret_cast<const short8*>(vg + 512 + lofs);
        short8 bv2 = *reinterpret_cast<const short8*>(vg + 1024 + lofs);
        short8 bv3 = *reinterpret_cast<const short8*>(vg + 1536 + lofs);

        {
            f32x4 c0 = {0.f, 0.f, 0.f, 0.f};
            f32x4 c1 = {0.f, 0.f, 0.f, 0.f};
            c0 = __builtin_amdgcn_mfma_f32_16x16x32_bf16(k00, qa0A, c0, 0, 0, 0);
            c0 = __builtin_amdgcn_mfma_f32_16x16x32_bf16(k01, qa1A, c0, 0, 0, 0);
            c1 = __builtin_amdgcn_mfma_f32_16x16x32_bf16(k10, qa0A, c1, 0, 0, 0);
            c1 = __builtin_amdgcn_mfma_f32_16x16x32_bf16(k11, qa1A, c1, 0, 0, 0);
            float e0[4], e1[4];
            #pragma unroll
            for (int rr = 0; rr < 4; ++rr) {
                e0[rr] = __expf(c0[rr] * scale);
                e1[rr] = __expf(c1[rr] * scale);
                lA += e0[rr] + e1[rr];
            }
            int w00 = (int)pkbf(e0[0], e0[1]);
            int w01 = (int)pkbf(e0[2], e0[3]);
            int w10 = (int)pkbf(e1[0], e1[1]);
            int w11 = (int)pkbf(e1[2], e1[3]);
            int t0 = __builtin_amdgcn_ds_bpermute(srcA, w00);
            int t1 = __builtin_amdgcn_ds_bpermute(srcA, w01);
            int t2 = __builtin_amdgcn_ds_bpermute(srcB, w00);
            int t3 = __builtin_amdgcn_ds_bpermute(srcB, w01);
            int u0 = __builtin_amdgcn_ds_bpermute(srcA, w10);
            int u1 = __builtin_amdgcn_ds_bpermute(srcA, w11);
            int u2 = __builtin_amdgcn_ds_bpermute(srcB, w10);
            int u3 = __builtin_amdgcn_ds_bpermute(srcB, w11);
            union { short8 s8; int wd[4]; } fr;
            fr.wd[0] = glow ? t0 : u0;
            fr.wd[1] = glow ? t1 : u1;
            fr.wd[2] = glow ? t2 : u2;
            fr.wd[3] = glow ? t3 : u3;
            accA[0] = __builtin_amdgcn_mfma_f32_16x16x32_bf16(fr.s8, bv0, accA[0], 0, 0, 0);
            accA[1] = __builtin_amdgcn_mfma_f32_16x16x32_bf16(fr.s8, bv1, accA[1], 0, 0, 0);
            accA[2] = __builtin_amdgcn_mfma_f32_16x16x32_bf16(fr.s8, bv2, accA[2], 0, 0, 0);
            accA[3] = __builtin_amdgcn_mfma_f32_16x16x32_bf16(fr.s8, bv3, accA[3], 0, 0, 0);
        }
        {
            f32x4 c0 = {0.f, 0.f, 0.f, 0.f};
            f32x4 c1 = {0.f, 0.f, 0.f, 0.f};
            c0 = __builtin_amdgcn_mfma_f32_16x16x32_bf16(k00, qa0B, c0, 0, 0, 0);
            c0 = __builtin_amdgcn_mfma_f32_16x16x32_bf16(k01, qa1B, c0, 0, 0, 0);
            c1 = __builtin_amdgcn_mfma_f32_16x16x32_bf16(k10, qa0B, c1, 0, 0, 0);
            c1 = __builtin_amdgcn_mfma_f32_16x16x32_bf16(k11, qa1B, c1, 0, 0, 0);
            float e0[4], e1[4];
            #pragma unroll
            for (int rr = 0; rr < 4; ++rr) {
                e0[rr] = __expf(c0[rr] * scale);
                e1[rr] = __expf(c1[rr] * scale);
                lB += e0[rr] + e1[rr];
            }
            int w00 = (int)pkbf(e0[0], e0[1]);
            int w01 = (int)pkbf(e0[2], e0[3]);
            int w10 = (int)pkbf(e1[0], e1[1]);
            int w11 = (int)pkbf(e1[2], e1[3]);
            int t0 = __builtin_amdgcn_ds_bpermute(srcA, w00);
            int t1 = __builtin_amdgcn_ds_bpermute(srcA, w01);
            int t2 = __builtin_amdgcn_ds_bpermute(srcB, w00);
            int t3 = __builtin_amdgcn_ds_bpermute(srcB, w01);
            int u0 = __builtin_amdgcn_ds_bpermute(srcA, w10);
            int u1 = __builtin_amdgcn_ds_bpermute(srcA, w11);
            int u2 = __builtin_amdgcn_ds_bpermute(srcB, w10);
            int u3 = __builtin_amdgcn_ds_bpermute(srcB, w11);
            union { short8 s8; int wd[4]; } fr;
            fr.wd[0] = glow ? t0 : u0;
            fr.wd[1] = glow ? t1 : u1;
            fr.wd[2] = glow ? t2 : u2;
            fr.wd[3] = glow ? t3 : u3;
            accB[0] = __builtin_amdgcn_mfma_f32_16x16x32_bf16(fr.s8, bv0, accB[0], 0, 0, 0);
            accB[1] = __builtin_amdgcn_mfma_f32_16x16x32_bf16(fr.s8, bv1, accB[1], 0, 0, 0);
            accB[2] = __builtin_amdgcn_mfma_f32_16x16x32_bf16(fr.s8, bv2, accB[2], 0, 0, 0);
            accB[3] = __builtin_amdgcn_mfma_f32_16x16x32_bf16(fr.s8, bv3, accB[3], 0, 0, 0);
        }
    }
    lA += __shfl_xor(lA, 16);  lA += __shfl_xor(lA, 32);
    lB += __shfl_xor(lB, 16);  lB += __shfl_xor(lB, 32);
    const float rlA = 1.0f / lA;                       // denom for q = qb+lrow
    const float rlB = 1.0f / lB;                       // denom for q = qb+16+lrow

    // ---- pass 2: P stream; each K load feeds both subtiles ----
    char* stgA = (char*)&stage[w][0][0][0];
    char* stgB = (char*)&stage[w][1][0][0];
    const int swz = (lrow & 7) << 4;
    float* Pb = P + (size_t)bh * S_LEN * S_LEN;

    for (int sup = 0; sup < S_LEN; sup += SUP) {
        #pragma unroll
        for (int jj = 0; jj < SUP / 32; ++jj) {
            const int j0 = sup + jj * 32;
            const short* kg = Kp + (size_t)(j0 >> 4) * 1024;
            short8 k00 = *reinterpret_cast<const short8*>(kg + lofs);
            short8 k01 = *reinterpret_cast<const short8*>(kg + 512 + lofs);
            short8 k10 = *reinterpret_cast<const short8*>(kg + 1024 + lofs);
            short8 k11 = *reinterpret_cast<const short8*>(kg + 1536 + lofs);
            const int o0 = (lrow * 512 + ((jj * 32 + lgrp * 4) << 2)) ^ swz;
            const int o1 = (lrow * 512 + ((jj * 32 + 16 + lgrp * 4) << 2)) ^ swz;
            {
                f32x4 c0 = {0.f, 0.f, 0.f, 0.f};
                f32x4 c1 = {0.f, 0.f, 0.f, 0.f};
                c0 = __builtin_amdgcn_mfma_f32_16x16x32_bf16(k00, qa0A, c0, 0, 0, 0);
                c0 = __builtin_amdgcn_mfma_f32_16x16x32_bf16(k01, qa1A, c0, 0, 0, 0);
                c1 = __builtin_amdgcn_mfma_f32_16x16x32_bf16(k10, qa0A, c1, 0, 0, 0);
                c1 = __builtin_amdgcn_mfma_f32_16x16x32_bf16(k11, qa1A, c1, 0, 0, 0);
                f32x4 p0, p1;
                #pragma unroll
                for (int rr = 0; rr < 4; ++rr) {
                    p0[rr] = __expf(c0[rr] * scale) * rlA;
                    p1[rr] = __expf(c1[rr] * scale) * rlA;
                }
                *(f32x4*)(stgA + o0) = p0;
                *(f32x4*)(stgA + o1) = p1;
            }
            {
                f32x4 c0 = {0.f, 0.f, 0.f, 0.f};
                f32x4 c1 = {0.f, 0.f, 0.f, 0.f};
                c0 = __builtin_amdgcn_mfma_f32_16x16x32_bf16(k00, qa0B, c0, 0, 0, 0);
                c0 = __builtin_amdgcn_mfma_f32_16x16x32_bf16(k01, qa1B, c0, 0, 0, 0);
                c1 = __builtin_amdgcn_mfma_f32_16x16x32_bf16(k10, qa0B, c1, 0, 0, 0);
                c1 = __builtin_amdgcn_mfma_f32_16x16x32_bf16(k11, qa1B, c1, 0, 0, 0);
                f32x4 p0, p1;
                #pragma unroll
                for (int rr = 0; rr < 4; ++rr) {
                    p0[rr] = __expf(c0[rr] * scale) * rlB;
                    p1[rr] = __expf(c1[rr] * scale) * rlB;
                }
                *(f32x4*)(stgB + o0) = p0;
                *(f32x4*)(stgB + o1) = p1;
            }
        }

        asm volatile("s_waitcnt lgkmcnt(0)" ::: "memory");
        #pragma unroll
        for (int rb = 0; rb < 8; ++rb) {
            const int r = rb * 2 + (lane >> 5);
            const int c = lane & 31;
            f32x4 pv = *(const f32x4*)(stgA + ((r * 512 + c * 16) ^ ((r & 7) << 4)));
            *(f32x4*)(Pb + (size_t)(qb + r) * S_LEN + sup + c * 4) = pv;
        }
        #pragma unroll
        for (int rb = 0; rb < 8; ++rb) {
            const int r = rb * 2 + (lane >> 5);
            const int c = lane & 31;
            f32x4 pv = *(const f32x4*)(stgB + ((r * 512 + c * 16) ^ ((r & 7) << 4)));
            *(f32x4*)(Pb + (size_t)(qb + 16 + r) * S_LEN + sup + c * 4) = pv;
        }
        asm volatile("s_waitcnt lgkmcnt(0)" ::: "memory");
    }

    // ---- epilogue: Out rows for both subtiles ----
    float rloA[4], rloB[4];
    #pragma unroll
    for (int rr = 0; rr < 4; ++rr) {
        rloA[rr] = __shfl(rlA, lgrp * 4 + rr);
        rloB[rr] = __shfl(rlB, lgrp * 4 + rr);
    }
    float* obA = Out + ((size_t)bh * S_LEN + qb + lgrp * 4) * D_HEAD + lrow;
    float* obB = obA + (size_t)16 * D_HEAD;
    #pragma unroll
    for (int vt = 0; vt < 4; ++vt) {
        #pragma unroll
        for (int rr = 0; rr < 4; ++rr) {
            obA[(size_t)rr * D_HEAD + vt * 16] = accA[vt][rr] * rloA[rr];
            obB[(size_t)rr * D_HEAD + vt * 16] = accB[vt][rr] * rloB[rr];
        }
    }
}

extern "C" void kernel_launch(void* const* d_in, const int* in_sizes, int n_in,
                              void* d_out, int out_size, void* d_ws, size_t ws_size,
                              hipStream_t stream) {
    const float* Q = (const float*)d_in[0];
    const float* K = (const float*)d_in[1];
    const float* V = (const float*)d_in[2];
    float* Out = (float*)d_out;
    float* P = Out + (size_t)NELEM;                    // outputs concatenated flat
    short* Kf = (short*)d_ws;                          // 8.4 MB
    short* Vf = Kf + (size_t)NELEM;                    // 8.4 MB (needs ws >= 16.8 MB)

    convert_kf_kernel<<<NELEM / (256 * 8), 256, 0, stream>>>(K, Kf);
    transpose_vf_kernel<<<dim3(S_LEN / 64, NBH), 256, 0, stream>>>(V, Vf);
    attn_kernel<<<dim3(S_LEN / 128, NBH), 256, 0, stream>>>(Q, Kf, Vf, Out, P);
}

// Round 12
// 175.498 us; speedup vs baseline: 2.5264x; 1.0683x over previous
//
#include <hip/hip_runtime.h>
#include <hip/hip_bf16.h>
#include <cstdint>
#include <cstddef>

#define S_LEN 2048
#define D_HEAD 64
#define NBH 32                      // B*H = 2*16
#define NELEM 4194304               // NBH * S_LEN * D_HEAD
#define SUP 128                     // columns per store superblock

typedef __attribute__((ext_vector_type(8))) short short8;
typedef __attribute__((ext_vector_type(4))) float f32x4;

__device__ __forceinline__ short f2bf(float f) {
    union { float f; uint32_t u; } v; v.f = f;
    uint32_t u = v.u + 0x7FFFu + ((v.u >> 16) & 1u);   // RNE, inputs finite
    return (short)(u >> 16);
}

__device__ __forceinline__ uint32_t pkbf(float lo, float hi) {
    return ((uint32_t)(uint16_t)f2bf(hi) << 16) | (uint32_t)(uint16_t)f2bf(lo);
}

// K fp32 -> fragment-major bf16:
// Kf slot s = ((bh*128 + g)*2 + p)*64 + l holds K[bh][g*16 + (l&15)][p*32 + (l>>4)*8 + e]
__global__ void convert_kf_kernel(const float* __restrict__ K, short* __restrict__ Kf) {
    const int s = blockIdx.x * 256 + threadIdx.x;      // 524288 slots total
    const int l = s & 63;
    const int p = (s >> 6) & 1;
    const int g = (s >> 7) & 127;
    const int bh = s >> 14;
    const float* src = K + ((size_t)bh * S_LEN + g * 16 + (l & 15)) * D_HEAD
                         + p * 32 + (l >> 4) * 8;
    short8 y;
    #pragma unroll
    for (int e = 0; e < 8; ++e) y[e] = f2bf(src[e]);
    *reinterpret_cast<short8*>(Kf + (size_t)s * 8) = y;
}

// V fp32 [bh][S][D] -> fragment-major bf16:
// Vf slot s = ((bh*64 + t)*4 + vt)*64 + l holds V[bh][t*32 + (l>>4)*8 + e][vt*16 + (l&15)]
__global__ void transpose_vf_kernel(const float* __restrict__ V, short* __restrict__ Vf) {
    __shared__ float tile[64][65];
    const int bh = blockIdx.y;
    const int s0 = blockIdx.x * 64;
    const int d = threadIdx.x & 63;
    const int r = threadIdx.x >> 6;
    const float* vp = V + ((size_t)bh * S_LEN + s0) * D_HEAD;
    #pragma unroll
    for (int i = 0; i < 16; ++i) {
        int srow = i * 4 + r;
        tile[srow][d] = vp[(size_t)srow * D_HEAD + d];
    }
    __syncthreads();
    #pragma unroll
    for (int h = 0; h < 2; ++h) {
        const int sl = h * 256 + threadIdx.x;          // 512 slots per block
        const int ti = sl >> 8;                        // j-subtile 0..1
        const int vt = (sl >> 6) & 3;
        const int l  = sl & 63;
        const int lrow = l & 15, lgrp = l >> 4;
        short8 y;
        #pragma unroll
        for (int e = 0; e < 8; ++e)
            y[e] = f2bf(tile[ti * 32 + lgrp * 8 + e][vt * 16 + lrow]);
        *reinterpret_cast<short8*>(
            Vf + ((((size_t)bh * 64 + (s0 >> 5) + ti) * 4 + vt) * 64 + l) * 8) = y;
    }
}

// Fused attention (R11 structure + counted-vmcnt store decoupling):
// wave = 32 q-rows (2 subtiles sharing K/V regs), fragment-major K/V loads,
// XCD-aware block swizzle, LDS-staged burst P stores (now nontemporal).
// NEW: next superstep's 16 K-fragments are register-prefetched BEFORE the
// store burst, so load-consume waits are vmcnt(>=16) — satisfied without the
// younger stores retiring (in-order vmcnt FIFO). Waves pace at HBM drain
// instead of serializing a full store-ack latency per superstep.
__launch_bounds__(256, 2)
__global__ void attn_kernel(const float* __restrict__ Q,
                            const short* __restrict__ Kf,
                            const short* __restrict__ Vf,
                            float* __restrict__ Out,
                            float* __restrict__ P) {
    __shared__ __align__(16) float stage[4][2][16][SUP];   // 64 KB

    const int lane = threadIdx.x & 63;
    const int w    = threadIdx.x >> 6;
    // XCD swizzle: b = dispatch-linear id; swz bijective on [0,512)
    const int b    = blockIdx.y * 16 + blockIdx.x;
    const int swzb = (b & 7) * 64 + (b >> 3);
    const int bx   = swzb & 15;
    const int bh   = swzb >> 4;
    const int qb   = bx * 128 + w * 32;                // wave's 32-row base
    const int lrow = lane & 15;
    const int lgrp = lane >> 4;
    const float scale = 0.125f;                        // 1/sqrt(64)

    short8 qa0A, qa1A, qa0B, qa1B;
    {
        const float* qrA = Q + ((size_t)bh * S_LEN + qb + lrow) * D_HEAD + lgrp * 8;
        const float* qrB = qrA + 16 * D_HEAD;
        #pragma unroll
        for (int e = 0; e < 8; ++e) qa0A[e] = f2bf(qrA[e]);
        #pragma unroll
        for (int e = 0; e < 8; ++e) qa1A[e] = f2bf(qrA[e + 32]);
        #pragma unroll
        for (int e = 0; e < 8; ++e) qa0B[e] = f2bf(qrB[e]);
        #pragma unroll
        for (int e = 0; e < 8; ++e) qa1B[e] = f2bf(qrB[e + 32]);
    }

    const short* Kp = Kf + (size_t)bh * (S_LEN * D_HEAD);
    const short* Vp = Vf + (size_t)bh * (S_LEN * D_HEAD);
    const int lofs = lane * 8;

    const int srcA = ((lane & 15) + ((lane >> 4) & 1) * 32) << 2;
    const int srcB = srcA + (16 << 2);
    const bool glow = (lgrp < 2);

    // ---- pass 1: denominators + PV (unnormalized e) for both subtiles ----
    float lA = 0.f, lB = 0.f;
    f32x4 accA[4] = {}, accB[4] = {};
    for (int j0 = 0; j0 < S_LEN; j0 += 32) {
        const short* kg = Kp + (size_t)(j0 >> 4) * 1024;
        short8 k00 = *reinterpret_cast<const short8*>(kg + lofs);
        short8 k01 = *reinterpret_cast<const short8*>(kg + 512 + lofs);
        short8 k10 = *reinterpret_cast<const short8*>(kg + 1024 + lofs);
        short8 k11 = *reinterpret_cast<const short8*>(kg + 1536 + lofs);
        const short* vg = Vp + (size_t)(j0 >> 5) * 2048;
        short8 bv0 = *reinterpret_cast<const short8*>(vg + lofs);
        short8 bv1 = *reinterpret_cast<const short8*>(vg + 512 + lofs);
        short8 bv2 = *reinterpret_cast<const short8*>(vg + 1024 + lofs);
        short8 bv3 = *reinterpret_cast<const short8*>(vg + 1536 + lofs);

        {
            f32x4 c0 = {0.f, 0.f, 0.f, 0.f};
            f32x4 c1 = {0.f, 0.f, 0.f, 0.f};
            c0 = __builtin_amdgcn_mfma_f32_16x16x32_bf16(k00, qa0A, c0, 0, 0, 0);
            c0 = __builtin_amdgcn_mfma_f32_16x16x32_bf16(k01, qa1A, c0, 0, 0, 0);
            c1 = __builtin_amdgcn_mfma_f32_16x16x32_bf16(k10, qa0A, c1, 0, 0, 0);
            c1 = __builtin_amdgcn_mfma_f32_16x16x32_bf16(k11, qa1A, c1, 0, 0, 0);
            float e0[4], e1[4];
            #pragma unroll
            for (int rr = 0; rr < 4; ++rr) {
                e0[rr] = __expf(c0[rr] * scale);
                e1[rr] = __expf(c1[rr] * scale);
                lA += e0[rr] + e1[rr];
            }
            int w00 = (int)pkbf(e0[0], e0[1]);
            int w01 = (int)pkbf(e0[2], e0[3]);
            int w10 = (int)pkbf(e1[0], e1[1]);
            int w11 = (int)pkbf(e1[2], e1[3]);
            int t0 = __builtin_amdgcn_ds_bpermute(srcA, w00);
            int t1 = __builtin_amdgcn_ds_bpermute(srcA, w01);
            int t2 = __builtin_amdgcn_ds_bpermute(srcB, w00);
            int t3 = __builtin_amdgcn_ds_bpermute(srcB, w01);
            int u0 = __builtin_amdgcn_ds_bpermute(srcA, w10);
            int u1 = __builtin_amdgcn_ds_bpermute(srcA, w11);
            int u2 = __builtin_amdgcn_ds_bpermute(srcB, w10);
            int u3 = __builtin_amdgcn_ds_bpermute(srcB, w11);
            union { short8 s8; int wd[4]; } fr;
            fr.wd[0] = glow ? t0 : u0;
            fr.wd[1] = glow ? t1 : u1;
            fr.wd[2] = glow ? t2 : u2;
            fr.wd[3] = glow ? t3 : u3;
            accA[0] = __builtin_amdgcn_mfma_f32_16x16x32_bf16(fr.s8, bv0, accA[0], 0, 0, 0);
            accA[1] = __builtin_amdgcn_mfma_f32_16x16x32_bf16(fr.s8, bv1, accA[1], 0, 0, 0);
            accA[2] = __builtin_amdgcn_mfma_f32_16x16x32_bf16(fr.s8, bv2, accA[2], 0, 0, 0);
            accA[3] = __builtin_amdgcn_mfma_f32_16x16x32_bf16(fr.s8, bv3, accA[3], 0, 0, 0);
        }
        {
            f32x4 c0 = {0.f, 0.f, 0.f, 0.f};
            f32x4 c1 = {0.f, 0.f, 0.f, 0.f};
            c0 = __builtin_amdgcn_mfma_f32_16x16x32_bf16(k00, qa0B, c0, 0, 0, 0);
            c0 = __builtin_amdgcn_mfma_f32_16x16x32_bf16(k01, qa1B, c0, 0, 0, 0);
            c1 = __builtin_amdgcn_mfma_f32_16x16x32_bf16(k10, qa0B, c1, 0, 0, 0);
            c1 = __builtin_amdgcn_mfma_f32_16x16x32_bf16(k11, qa1B, c1, 0, 0, 0);
            float e0[4], e1[4];
            #pragma unroll
            for (int rr = 0; rr < 4; ++rr) {
                e0[rr] = __expf(c0[rr] * scale);
                e1[rr] = __expf(c1[rr] * scale);
                lB += e0[rr] + e1[rr];
            }
            int w00 = (int)pkbf(e0[0], e0[1]);
            int w01 = (int)pkbf(e0[2], e0[3]);
            int w10 = (int)pkbf(e1[0], e1[1]);
            int w11 = (int)pkbf(e1[2], e1[3]);
            int t0 = __builtin_amdgcn_ds_bpermute(srcA, w00);
            int t1 = __builtin_amdgcn_ds_bpermute(srcA, w01);
            int t2 = __builtin_amdgcn_ds_bpermute(srcB, w00);
            int t3 = __builtin_amdgcn_ds_bpermute(srcB, w01);
            int u0 = __builtin_amdgcn_ds_bpermute(srcA, w10);
            int u1 = __builtin_amdgcn_ds_bpermute(srcA, w11);
            int u2 = __builtin_amdgcn_ds_bpermute(srcB, w10);
            int u3 = __builtin_amdgcn_ds_bpermute(srcB, w11);
            union { short8 s8; int wd[4]; } fr;
            fr.wd[0] = glow ? t0 : u0;
            fr.wd[1] = glow ? t1 : u1;
            fr.wd[2] = glow ? t2 : u2;
            fr.wd[3] = glow ? t3 : u3;
            accB[0] = __builtin_amdgcn_mfma_f32_16x16x32_bf16(fr.s8, bv0, accB[0], 0, 0, 0);
            accB[1] = __builtin_amdgcn_mfma_f32_16x16x32_bf16(fr.s8, bv1, accB[1], 0, 0, 0);
            accB[2] = __builtin_amdgcn_mfma_f32_16x16x32_bf16(fr.s8, bv2, accB[2], 0, 0, 0);
            accB[3] = __builtin_amdgcn_mfma_f32_16x16x32_bf16(fr.s8, bv3, accB[3], 0, 0, 0);
        }
    }
    lA += __shfl_xor(lA, 16);  lA += __shfl_xor(lA, 32);
    lB += __shfl_xor(lB, 16);  lB += __shfl_xor(lB, 32);
    const float rlA = 1.0f / lA;                       // denom for q = qb+lrow
    const float rlB = 1.0f / lB;                       // denom for q = qb+16+lrow

    // ---- epilogue for Out (before the store-heavy pass 2) ----
    {
        float rloA[4], rloB[4];
        #pragma unroll
        for (int rr = 0; rr < 4; ++rr) {
            rloA[rr] = __shfl(rlA, lgrp * 4 + rr);
            rloB[rr] = __shfl(rlB, lgrp * 4 + rr);
        }
        float* obA = Out + ((size_t)bh * S_LEN + qb + lgrp * 4) * D_HEAD + lrow;
        float* obB = obA + (size_t)16 * D_HEAD;
        #pragma unroll
        for (int vt = 0; vt < 4; ++vt) {
            #pragma unroll
            for (int rr = 0; rr < 4; ++rr) {
                obA[(size_t)rr * D_HEAD + vt * 16] = accA[vt][rr] * rloA[rr];
                obB[(size_t)rr * D_HEAD + vt * 16] = accB[vt][rr] * rloB[rr];
            }
        }
    }

    // ---- pass 2: P stream with prefetched K (loads issued BEFORE stores) ----
    char* stgA = (char*)&stage[w][0][0][0];
    char* stgB = (char*)&stage[w][1][0][0];
    const int swz = (lrow & 7) << 4;
    float* Pb = P + (size_t)bh * S_LEN * S_LEN;

    short8 pk00[4], pk01[4], pk10[4], pk11[4];         // next-superstep K frags
    #pragma unroll
    for (int jj = 0; jj < 4; ++jj) {
        const short* kg = Kp + (size_t)((jj * 32) >> 4) * 1024;
        pk00[jj] = *reinterpret_cast<const short8*>(kg + lofs);
        pk01[jj] = *reinterpret_cast<const short8*>(kg + 512 + lofs);
        pk10[jj] = *reinterpret_cast<const short8*>(kg + 1024 + lofs);
        pk11[jj] = *reinterpret_cast<const short8*>(kg + 1536 + lofs);
    }

    for (int sup = 0; sup < S_LEN; sup += SUP) {
        // compute phase: consume prefetched K (oldest in vmcnt FIFO)
        #pragma unroll
        for (int jj = 0; jj < SUP / 32; ++jj) {
            short8 k00 = pk00[jj], k01 = pk01[jj], k10 = pk10[jj], k11 = pk11[jj];
            const int o0 = (lrow * 512 + ((jj * 32 + lgrp * 4) << 2)) ^ swz;
            const int o1 = (lrow * 512 + ((jj * 32 + 16 + lgrp * 4) << 2)) ^ swz;
            {
                f32x4 c0 = {0.f, 0.f, 0.f, 0.f};
                f32x4 c1 = {0.f, 0.f, 0.f, 0.f};
                c0 = __builtin_amdgcn_mfma_f32_16x16x32_bf16(k00, qa0A, c0, 0, 0, 0);
                c0 = __builtin_amdgcn_mfma_f32_16x16x32_bf16(k01, qa1A, c0, 0, 0, 0);
                c1 = __builtin_amdgcn_mfma_f32_16x16x32_bf16(k10, qa0A, c1, 0, 0, 0);
                c1 = __builtin_amdgcn_mfma_f32_16x16x32_bf16(k11, qa1A, c1, 0, 0, 0);
                f32x4 p0, p1;
                #pragma unroll
                for (int rr = 0; rr < 4; ++rr) {
                    p0[rr] = __expf(c0[rr] * scale) * rlA;
                    p1[rr] = __expf(c1[rr] * scale) * rlA;
                }
                *(f32x4*)(stgA + o0) = p0;
                *(f32x4*)(stgA + o1) = p1;
            }
            {
                f32x4 c0 = {0.f, 0.f, 0.f, 0.f};
                f32x4 c1 = {0.f, 0.f, 0.f, 0.f};
                c0 = __builtin_amdgcn_mfma_f32_16x16x32_bf16(k00, qa0B, c0, 0, 0, 0);
                c0 = __builtin_amdgcn_mfma_f32_16x16x32_bf16(k01, qa1B, c0, 0, 0, 0);
                c1 = __builtin_amdgcn_mfma_f32_16x16x32_bf16(k10, qa0B, c1, 0, 0, 0);
                c1 = __builtin_amdgcn_mfma_f32_16x16x32_bf16(k11, qa1B, c1, 0, 0, 0);
                f32x4 p0, p1;
                #pragma unroll
                for (int rr = 0; rr < 4; ++rr) {
                    p0[rr] = __expf(c0[rr] * scale) * rlB;
                    p1[rr] = __expf(c1[rr] * scale) * rlB;
                }
                *(f32x4*)(stgB + o0) = p0;
                *(f32x4*)(stgB + o1) = p1;
            }
        }

        asm volatile("s_waitcnt lgkmcnt(0)" ::: "memory");

        // prefetch next superstep's K BEFORE the store burst (counted-vmcnt
        // decoupling: these loads are older than the stores below)
        {
            const int nsup = (sup + SUP < S_LEN) ? (sup + SUP) : 0;
            #pragma unroll
            for (int jj = 0; jj < 4; ++jj) {
                const short* kg = Kp + (size_t)((nsup + jj * 32) >> 4) * 1024;
                pk00[jj] = *reinterpret_cast<const short8*>(kg + lofs);
                pk01[jj] = *reinterpret_cast<const short8*>(kg + 512 + lofs);
                pk10[jj] = *reinterpret_cast<const short8*>(kg + 1024 + lofs);
                pk11[jj] = *reinterpret_cast<const short8*>(kg + 1536 + lofs);
            }
        }
        __builtin_amdgcn_sched_barrier(0);             // pin: loads stay above stores

        // burst store: 2 rows x 512B per instruction, nontemporal (P is
        // never re-read; keep the 537MB stream out of L2 so K/V stay resident)
        #pragma unroll
        for (int rb = 0; rb < 8; ++rb) {
            const int r = rb * 2 + (lane >> 5);
            const int c = lane & 31;
            f32x4 pv = *(const f32x4*)(stgA + ((r * 512 + c * 16) ^ ((r & 7) << 4)));
            __builtin_nontemporal_store(pv,
                (f32x4*)(Pb + (size_t)(qb + r) * S_LEN + sup + c * 4));
        }
        #pragma unroll
        for (int rb = 0; rb < 8; ++rb) {
            const int r = rb * 2 + (lane >> 5);
            const int c = lane & 31;
            f32x4 pv = *(const f32x4*)(stgB + ((r * 512 + c * 16) ^ ((r & 7) << 4)));
            __builtin_nontemporal_store(pv,
                (f32x4*)(Pb + (size_t)(qb + 16 + r) * S_LEN + sup + c * 4));
        }
        asm volatile("s_waitcnt lgkmcnt(0)" ::: "memory");
    }
}

extern "C" void kernel_launch(void* const* d_in, const int* in_sizes, int n_in,
                              void* d_out, int out_size, void* d_ws, size_t ws_size,
                              hipStream_t stream) {
    const float* Q = (const float*)d_in[0];
    const float* K = (const float*)d_in[1];
    const float* V = (const float*)d_in[2];
    float* Out = (float*)d_out;
    float* P = Out + (size_t)NELEM;                    // outputs concatenated flat
    short* Kf = (short*)d_ws;                          // 8.4 MB
    short* Vf = Kf + (size_t)NELEM;                    // 8.4 MB (needs ws >= 16.8 MB)

    convert_kf_kernel<<<NELEM / (256 * 8), 256, 0, stream>>>(K, Kf);
    transpose_vf_kernel<<<dim3(S_LEN / 64, NBH), 256, 0, stream>>>(V, Vf);
    attn_kernel<<<dim3(S_LEN / 128, NBH), 256, 0, stream>>>(Q, Kf, Vf, Out, P);
}